// Round 7
// baseline (175.306 us; speedup 1.0000x reference)
//
#include <hip/hip_runtime.h>

// CapsNet forward.
// conv1 (fp32 compute) -> x1t f16 [B][ih=20][iw=20][ci=16]  (ci innermost)
// packWB: w2 -> MFMA B-fragments; conv2: mfma_32x32x16_f16 -> uT [144][B][8] f32
// packWr: W_route -> f16 c-pairs
// uhat_kernel: block=(i, 256-sample chunk), W[i] in LDS -> uhT [144][B][80dw] f16
// routing_kernel: per-sample LDS routing (3 iters, fp32 reductions) -> pred, v

typedef _Float16 half2_t __attribute__((ext_vector_type(2)));
typedef _Float16 f16x8 __attribute__((ext_vector_type(8)));
typedef float f32x16 __attribute__((ext_vector_type(16)));

static __device__ __forceinline__ float fdot2f(half2_t a, half2_t b, float c) {
#if __has_builtin(__builtin_amdgcn_fdot2)
  return __builtin_amdgcn_fdot2(a, b, c, false);
#else
  return c + (float)a[0] * (float)b[0] + (float)a[1] * (float)b[1];
#endif
}

static __device__ __forceinline__ half2_t h2(unsigned int u) {
  return __builtin_bit_cast(half2_t, u);
}

static __device__ __forceinline__ unsigned int pkh2(float a, float b) {
  half2_t h;
  h[0] = (_Float16)a;
  h[1] = (_Float16)b;
  return __builtin_bit_cast(unsigned int, h);
}

static __device__ __forceinline__ half2_t ph2(float a, float b) {
  half2_t h;
  h[0] = (_Float16)a;
  h[1] = (_Float16)b;
  return h;
}

static __device__ __forceinline__ f32x16 zero16() {
  f32x16 z = {0.f, 0.f, 0.f, 0.f, 0.f, 0.f, 0.f, 0.f,
              0.f, 0.f, 0.f, 0.f, 0.f, 0.f, 0.f, 0.f};
  return z;
}

// w2[co][ci][kh][kw] f32 -> wBg[((kh*9+kw)*64 + lane)*8 + j] f16
__global__ __launch_bounds__(256) void packWB(
    const float* __restrict__ w2, _Float16* __restrict__ wBg) {
  int idx = blockIdx.x * 256 + threadIdx.x;
  if (idx >= 41472) return;
  int j = idx & 7;
  int lane = (idx >> 3) & 63;
  int step = idx >> 9;
  int kh = step / 9, kw = step - kh * 9;
  int co = lane & 31, ci = (lane >> 5) * 8 + j;
  wBg[idx] = (_Float16)w2[(co * 16 + ci) * 81 + kh * 9 + kw];
}

// W_route [144][10][16][8] f32 -> wPr [(i*10+o)*16+d][4] f16 c-pairs
__global__ __launch_bounds__(256) void packWr(
    const float* __restrict__ W, unsigned int* __restrict__ wPr) {
  int idx = blockIdx.x * 256 + threadIdx.x;   // 92160 dwords
  if (idx >= 92160) return;
  int cp = idx & 3;
  int row = idx >> 2;
  const float* src = W + (size_t)row * 8 + cp * 2;
  wPr[idx] = pkh2(src[0], src[1]);
}

__global__ __launch_bounds__(320) void conv1_kernel(
    const float* __restrict__ in, const float* __restrict__ w,
    const float* __restrict__ bias, _Float16* __restrict__ x1t) {
  __shared__ __align__(16) float sIn[784];      // 28x28
  __shared__ float sW[1296];                    // 16x81
  __shared__ __align__(16) _Float16 sOut[6400]; // [ih][iw][ci]
  int b = blockIdx.x, t = threadIdx.x;
  const float* inb = in + b * 784;
  for (int i = t; i < 784; i += 320) sIn[i] = inb[i];
  for (int i = t; i < 1296; i += 320) sW[i] = w[i];
  __syncthreads();
  int co = t / 20, oh = t % 20;   // 16*20 = 320 work items
  float bv = bias[co];
  float acc[20];
#pragma unroll
  for (int j = 0; j < 20; ++j) acc[j] = bv;
#pragma unroll
  for (int kh = 0; kh < 9; ++kh) {
    float r[28];
    const float4* row = (const float4*)&sIn[(oh + kh) * 28];
#pragma unroll
    for (int q = 0; q < 7; ++q) {
      float4 v = row[q];
      r[q * 4 + 0] = v.x; r[q * 4 + 1] = v.y; r[q * 4 + 2] = v.z; r[q * 4 + 3] = v.w;
    }
    const float* wr = &sW[co * 81 + kh * 9];
#pragma unroll
    for (int kw = 0; kw < 9; ++kw) {
      float wv = wr[kw];
#pragma unroll
      for (int j = 0; j < 20; ++j) acc[j] += wv * r[kw + j];
    }
  }
#pragma unroll
  for (int j = 0; j < 20; ++j) sOut[(oh * 20 + j) * 16 + co] = (_Float16)acc[j];
  __syncthreads();
  const unsigned int* s4 = (const unsigned int*)sOut;
  unsigned int* g4 = (unsigned int*)(x1t + (size_t)b * 6400);
  for (int i = t; i < 3200; i += 320) g4[i] = s4[i];
}

// conv2 MFMA: block = 8 samples (288 rows = 9 M-tiles of 32), 4 waves.
// Stores u transposed: uT[i][b][c] for uhat_kernel's coalesced reads.
__global__ __launch_bounds__(256) void conv2_kernel(
    const _Float16* __restrict__ x1t, const _Float16* __restrict__ wBg,
    const float* __restrict__ bias, float* __restrict__ uT, int B) {
  __shared__ __align__(16) _Float16 sX[51200];  // 8 x [400][16]
  __shared__ __align__(16) _Float16 sB[4608];   // [kw 9][lane 64][8]
  int t = threadIdx.x;
  int bbase = blockIdx.x * 8;
  {
    const uint4* g = (const uint4*)(x1t + (size_t)bbase * 6400);
    uint4* s = (uint4*)sX;
#pragma unroll
    for (int i = 0; i < 25; ++i) s[t + i * 256] = g[t + i * 256];
  }
  int wv = t >> 6, lane = t & 63;
  int l31 = lane & 31, half = lane >> 5;
  int tbase0 = 0, tbase1 = 0, tbase2 = 0;
  {
    int r = wv * 32 + l31;
    int s = r / 36, pos = r - s * 36, oh = pos / 6, ow = pos - oh * 6;
    tbase0 = s * 6400 + (oh * 40 + ow * 2) * 16 + half * 8;
    r += 128;
    s = r / 36; pos = r - s * 36; oh = pos / 6; ow = pos - oh * 6;
    tbase1 = s * 6400 + (oh * 40 + ow * 2) * 16 + half * 8;
    if (wv == 0) {
      r = 256 + l31;
      s = r / 36; pos = r - s * 36; oh = pos / 6; ow = pos - oh * 6;
      tbase2 = s * 6400 + (oh * 40 + ow * 2) * 16 + half * 8;
    }
  }
  f32x16 acc0 = zero16(), acc1 = zero16(), acc2 = zero16();

  for (int kh = 0; kh < 9; ++kh) {
    __syncthreads();
    {
      const unsigned int* g = (const unsigned int*)(wBg + kh * 4608);
      unsigned int* s = (unsigned int*)sB;
#pragma unroll
      for (int i = 0; i < 9; ++i) s[t + i * 256] = g[t + i * 256];
    }
    __syncthreads();
    int abase = kh * 320;
#pragma unroll
    for (int kw = 0; kw < 9; ++kw) {
      f16x8 bf = *(const f16x8*)(sB + kw * 512 + lane * 8);
      f16x8 a0 = *(const f16x8*)(sX + tbase0 + abase + kw * 16);
      acc0 = __builtin_amdgcn_mfma_f32_32x32x16_f16(a0, bf, acc0, 0, 0, 0);
      f16x8 a1 = *(const f16x8*)(sX + tbase1 + abase + kw * 16);
      acc1 = __builtin_amdgcn_mfma_f32_32x32x16_f16(a1, bf, acc1, 0, 0, 0);
      if (wv == 0) {
        f16x8 a2 = *(const f16x8*)(sX + tbase2 + abase + kw * 16);
        acc2 = __builtin_amdgcn_mfma_f32_32x32x16_f16(a2, bf, acc2, 0, 0, 0);
      }
    }
  }
  float bv = bias[l31];
  int c8 = l31 >> 2;
  int ibco = (l31 & 3) * 36;
#pragma unroll
  for (int reg = 0; reg < 16; ++reg) {
    int rbase = (reg & 3) + 8 * (reg >> 2) + 4 * half;
    {
      int r = wv * 32 + rbase;
      int s = r / 36, pos = r - s * 36;
      uT[((size_t)(ibco + pos) * B + (bbase + s)) * 8 + c8] = acc0[reg] + bv;
    }
    {
      int r = wv * 32 + 128 + rbase;
      int s = r / 36, pos = r - s * 36;
      uT[((size_t)(ibco + pos) * B + (bbase + s)) * 8 + c8] = acc1[reg] + bv;
    }
    if (wv == 0) {
      int r = 256 + rbase;
      int s = r / 36, pos = r - s * 36;
      uT[((size_t)(ibco + pos) * B + (bbase + s)) * 8 + c8] = acc2[reg] + bv;
    }
  }
}

// u_hat: block = (i, 256-sample chunk). W[i] (2.5 KB) in LDS, read once per
// block -> W L2 traffic 755 MB -> 2.9 MB. Thread = one sample: 640 fdot2.
__global__ __launch_bounds__(256) void uhat_kernel(
    const float* __restrict__ uT, const unsigned int* __restrict__ wPr,
    unsigned int* __restrict__ uhT, int B) {
  __shared__ __align__(16) unsigned int sW[640];   // [o*16+d][4] c-pair dwords
  int nchunk = B >> 8;
  int i = blockIdx.x / nchunk, chunk = blockIdx.x % nchunk;
  int t = threadIdx.x;
  {
    const unsigned int* g = wPr + i * 640;
    for (int j = t; j < 640; j += 256) sW[j] = g[j];
  }
  __syncthreads();
  int b = chunk * 256 + t;
  const float* up = uT + ((size_t)i * B + b) * 8;
  float4 ua = *(const float4*)up;
  float4 ub = *(const float4*)(up + 4);
  half2_t u0 = ph2(ua.x, ua.y), u1 = ph2(ua.z, ua.w),
          u2 = ph2(ub.x, ub.y), u3 = ph2(ub.z, ub.w);
  const uint4* W4 = (const uint4*)sW;   // [160] rows (o*16+d)
  uint4* g = (uint4*)(uhT + ((size_t)i * B + b) * 80);
#pragma unroll
  for (int q = 0; q < 20; ++q) {   // q covers dp = q*4 .. q*4+3
    unsigned int o4[4];
#pragma unroll
    for (int e = 0; e < 4; ++e) {
      int dp = q * 4 + e;                       // dp = o*8 + dd
      int row = (dp >> 3) * 16 + (dp & 7) * 2;  // o*16 + dd*2
      uint4 w0 = W4[row], w1 = W4[row + 1];
      float a0 = fdot2f(h2(w0.x), u0,
                 fdot2f(h2(w0.y), u1,
                 fdot2f(h2(w0.z), u2, fdot2f(h2(w0.w), u3, 0.f))));
      float a1 = fdot2f(h2(w1.x), u0,
                 fdot2f(h2(w1.y), u1,
                 fdot2f(h2(w1.z), u2, fdot2f(h2(w1.w), u3, 0.f))));
      o4[e] = pkh2(a0, a1);
    }
    g[q] = make_uint4(o4[0], o4[1], o4[2], o4[3]);
  }
}

// routing: block = sample. u_hat loaded once from global into LDS (padded
// rows 80->82 dwords: kills 16-way bank conflict). 3 iters, fp32 reductions.
__global__ __launch_bounds__(256) void routing_kernel(
    const unsigned int* __restrict__ uhT, float* __restrict__ out, int B) {
  __shared__ unsigned int uhh[11808];   // [144][82] f16 d-pairs (80 used)
  __shared__ float blog[1440];          // b [144][10]
  __shared__ float cc[1440];            // c [144][10]
  __shared__ float spart[480];          // s partials [3][160]
  __shared__ float ss[160];             // s [10][16]
  __shared__ float vv[160];             // v [10][16]
  __shared__ unsigned int vvh[80];      // v f16 d-pairs
  int b = blockIdx.x, t = threadIdx.x;
  for (int idx = t; idx < 11520; idx += 256) {
    int i = idx / 80, dp = idx - i * 80;
    uhh[i * 82 + dp] = uhT[((size_t)i * B + b) * 80 + dp];
  }
  for (int i = t; i < 1440; i += 256) blog[i] = 0.f;
  __syncthreads();

  for (int it = 0; it < 3; ++it) {
    if (it > 0) {
      if (t < 144) {
        const float* br = &blog[t * 10];
        float mx = br[0];
#pragma unroll
        for (int o = 1; o < 10; ++o) mx = fmaxf(mx, br[o]);
        float e[10];
        float sum = 0.f;
#pragma unroll
        for (int o = 0; o < 10; ++o) { e[o] = __expf(br[o] - mx); sum += e[o]; }
        float inv = 1.0f / sum;
#pragma unroll
        for (int o = 0; o < 10; ++o) cc[t * 10 + o] = e[o] * inv;
      }
      __syncthreads();
    }
    // s partials: 240 threads = 3 i-chunks x 80 d-pairs
    if (t < 240) {
      int ch = t / 80, dp = t - ch * 80;
      int o = dp >> 3;
      float a0 = 0.f, a1 = 0.f;
      int i0 = ch * 48;
      if (it == 0) {
        for (int i = i0; i < i0 + 48; ++i) {
          half2_t h = h2(uhh[i * 82 + dp]);
          a0 += (float)h[0]; a1 += (float)h[1];
        }
      } else {
        for (int i = i0; i < i0 + 48; ++i) {
          float c = cc[i * 10 + o];
          half2_t h = h2(uhh[i * 82 + dp]);
          a0 += c * (float)h[0]; a1 += c * (float)h[1];
        }
      }
      spart[ch * 160 + dp * 2] = a0;
      spart[ch * 160 + dp * 2 + 1] = a1;
    }
    __syncthreads();
    if (t < 160) {
      float s = spart[t] + spart[160 + t] + spart[320 + t];
      ss[t] = (it == 0) ? s * 0.1f : s;   // it==0: softmax of zeros = 0.1
    }
    __syncthreads();
    if (t < 10) {
      float sq = 0.f;
#pragma unroll
      for (int d = 0; d < 16; ++d) { float x = ss[t * 16 + d]; sq += x * x; }
      float coef = (sq / (1.0f + sq)) / sqrtf(sq + 1e-8f);
#pragma unroll
      for (int q = 0; q < 8; ++q) {
        float v0 = coef * ss[t * 16 + 2 * q];
        float v1 = coef * ss[t * 16 + 2 * q + 1];
        vv[t * 16 + 2 * q] = v0;
        vv[t * 16 + 2 * q + 1] = v1;
        vvh[t * 8 + q] = pkh2(v0, v1);
      }
      if (it == 2) out[b * 10 + t] = coef * sqrtf(sq);   // pred = ||v||
    }
    __syncthreads();
    if (it < 2) {
      for (int idx = t; idx < 1440; idx += 256) {
        int i = idx / 10, o = idx - i * 10;
        const uint2* uhp = (const uint2*)&uhh[i * 82 + o * 8];
        const uint2* vp = (const uint2*)&vvh[o * 8];
        float dot = 0.f;
#pragma unroll
        for (int q = 0; q < 4; ++q) {
          uint2 A = uhp[q], V = vp[q];
          dot = fdot2f(h2(A.x), h2(V.x), fdot2f(h2(A.y), h2(V.y), dot));
        }
        blog[idx] += dot;
      }
      __syncthreads();
    }
  }
  if (t < 160) out[B * 10 + b * 160 + t] = vv[t];
}

extern "C" void kernel_launch(void* const* d_in, const int* in_sizes, int n_in,
                              void* d_out, int out_size, void* d_ws, size_t ws_size,
                              hipStream_t stream) {
  const float* in = (const float*)d_in[0];
  const float* w1 = (const float*)d_in[1];
  const float* b1 = (const float*)d_in[2];
  const float* w2 = (const float*)d_in[3];
  const float* b2 = (const float*)d_in[4];
  const float* Wr = (const float*)d_in[5];
  float* out = (float*)d_out;
  int B = in_sizes[0] / 784;
  float* wsf = (float*)d_ws;

  // Layout (floats). x1t and uhT share one region: x1t lives conv1->conv2,
  // uhT lives uhat->routing (disjoint lifetimes, sequential stream).
  float* uT = wsf;                                   // [144][B][8] = B*1152
  float* shared_rgn = wsf + (size_t)B * 1152;        // max(B*3200, B*11520)
  _Float16* x1t = (_Float16*)shared_rgn;             // B*6400 f16
  unsigned int* uhT = (unsigned int*)shared_rgn;     // 144*B*80 dw
  float* tail = shared_rgn + (size_t)B * 11520;
  _Float16* wBg = (_Float16*)tail;                   // 41472 f16 = 20736 f
  unsigned int* wPr = (unsigned int*)(tail + 20736); // 92160 dw

  packWB<<<162, 256, 0, stream>>>(w2, wBg);
  packWr<<<360, 256, 0, stream>>>(Wr, wPr);
  conv1_kernel<<<B, 320, 0, stream>>>(in, w1, b1, x1t);
  conv2_kernel<<<B / 8, 256, 0, stream>>>(x1t, wBg, b2, uT, B);
  uhat_kernel<<<144 * (B / 256), 256, 0, stream>>>(uT, wPr, uhT, B);
  routing_kernel<<<B, 256, 0, stream>>>(uhT, out, B);
}

// Round 8
// 139.601 us; speedup vs baseline: 1.2558x; 1.2558x over previous
//
#include <hip/hip_runtime.h>

// CapsNet forward.
// conv1 (fp32 compute) -> x1t f16 [B][ih=20][iw=20][ci=16]  (ci innermost)
// packWB: w2 -> MFMA B-fragments; conv2: mfma_32x32x16_f16 -> u [B][144][8] f32
// packWr: W_route -> f16 c-pairs
// routing2: 2 samples/block, 512 thr; u_hat f16 in LDS (never HBM);
//           W_route streamed from L2 once per block; 3 iters fp32.

typedef _Float16 half2_t __attribute__((ext_vector_type(2)));
typedef _Float16 f16x8 __attribute__((ext_vector_type(8)));
typedef float f32x16 __attribute__((ext_vector_type(16)));

static __device__ __forceinline__ float fdot2f(half2_t a, half2_t b, float c) {
#if __has_builtin(__builtin_amdgcn_fdot2)
  return __builtin_amdgcn_fdot2(a, b, c, false);
#else
  return c + (float)a[0] * (float)b[0] + (float)a[1] * (float)b[1];
#endif
}

static __device__ __forceinline__ half2_t h2(unsigned int u) {
  return __builtin_bit_cast(half2_t, u);
}

static __device__ __forceinline__ unsigned int pkh2(float a, float b) {
  half2_t h;
  h[0] = (_Float16)a;
  h[1] = (_Float16)b;
  return __builtin_bit_cast(unsigned int, h);
}

static __device__ __forceinline__ f32x16 zero16() {
  f32x16 z = {0.f, 0.f, 0.f, 0.f, 0.f, 0.f, 0.f, 0.f,
              0.f, 0.f, 0.f, 0.f, 0.f, 0.f, 0.f, 0.f};
  return z;
}

// w2[co][ci][kh][kw] f32 -> wBg[((kh*9+kw)*64 + lane)*8 + j] f16
__global__ __launch_bounds__(256) void packWB(
    const float* __restrict__ w2, _Float16* __restrict__ wBg) {
  int idx = blockIdx.x * 256 + threadIdx.x;
  if (idx >= 41472) return;
  int j = idx & 7;
  int lane = (idx >> 3) & 63;
  int step = idx >> 9;
  int kh = step / 9, kw = step - kh * 9;
  int co = lane & 31, ci = (lane >> 5) * 8 + j;
  wBg[idx] = (_Float16)w2[(co * 16 + ci) * 81 + kh * 9 + kw];
}

// W_route [144][10][16][8] f32 -> wPr [(i*10+o)*16+d][4] f16 c-pairs
__global__ __launch_bounds__(256) void packWr(
    const float* __restrict__ W, unsigned int* __restrict__ wPr) {
  int idx = blockIdx.x * 256 + threadIdx.x;   // 92160 dwords
  if (idx >= 92160) return;
  int cp = idx & 3;
  int row = idx >> 2;
  const float* src = W + (size_t)row * 8 + cp * 2;
  wPr[idx] = pkh2(src[0], src[1]);
}

__global__ __launch_bounds__(320) void conv1_kernel(
    const float* __restrict__ in, const float* __restrict__ w,
    const float* __restrict__ bias, _Float16* __restrict__ x1t) {
  __shared__ __align__(16) float sIn[784];      // 28x28
  __shared__ float sW[1296];                    // 16x81
  __shared__ __align__(16) _Float16 sOut[6400]; // [ih][iw][ci]
  int b = blockIdx.x, t = threadIdx.x;
  const float* inb = in + b * 784;
  for (int i = t; i < 784; i += 320) sIn[i] = inb[i];
  for (int i = t; i < 1296; i += 320) sW[i] = w[i];
  __syncthreads();
  int co = t / 20, oh = t % 20;   // 16*20 = 320 work items
  float bv = bias[co];
  float acc[20];
#pragma unroll
  for (int j = 0; j < 20; ++j) acc[j] = bv;
#pragma unroll
  for (int kh = 0; kh < 9; ++kh) {
    float r[28];
    const float4* row = (const float4*)&sIn[(oh + kh) * 28];
#pragma unroll
    for (int q = 0; q < 7; ++q) {
      float4 v = row[q];
      r[q * 4 + 0] = v.x; r[q * 4 + 1] = v.y; r[q * 4 + 2] = v.z; r[q * 4 + 3] = v.w;
    }
    const float* wr = &sW[co * 81 + kh * 9];
#pragma unroll
    for (int kw = 0; kw < 9; ++kw) {
      float wv = wr[kw];
#pragma unroll
      for (int j = 0; j < 20; ++j) acc[j] += wv * r[kw + j];
    }
  }
#pragma unroll
  for (int j = 0; j < 20; ++j) sOut[(oh * 20 + j) * 16 + co] = (_Float16)acc[j];
  __syncthreads();
  const unsigned int* s4 = (const unsigned int*)sOut;
  unsigned int* g4 = (unsigned int*)(x1t + (size_t)b * 6400);
  for (int i = t; i < 3200; i += 320) g4[i] = s4[i];
}

// conv2 MFMA: block = 8 samples (288 rows = 9 M-tiles of 32), 4 waves.
// Stores u[b][i][c] f32 (contiguous per sample, for routing2's staging).
__global__ __launch_bounds__(256) void conv2_kernel(
    const _Float16* __restrict__ x1t, const _Float16* __restrict__ wBg,
    const float* __restrict__ bias, float* __restrict__ u) {
  __shared__ __align__(16) _Float16 sX[51200];  // 8 x [400][16]
  __shared__ __align__(16) _Float16 sB[4608];   // [kw 9][lane 64][8]
  int t = threadIdx.x;
  int bbase = blockIdx.x * 8;
  {
    const uint4* g = (const uint4*)(x1t + (size_t)bbase * 6400);
    uint4* s = (uint4*)sX;
#pragma unroll
    for (int i = 0; i < 25; ++i) s[t + i * 256] = g[t + i * 256];
  }
  int wv = t >> 6, lane = t & 63;
  int l31 = lane & 31, half = lane >> 5;
  int tbase0 = 0, tbase1 = 0, tbase2 = 0;
  {
    int r = wv * 32 + l31;
    int s = r / 36, pos = r - s * 36, oh = pos / 6, ow = pos - oh * 6;
    tbase0 = s * 6400 + (oh * 40 + ow * 2) * 16 + half * 8;
    r += 128;
    s = r / 36; pos = r - s * 36; oh = pos / 6; ow = pos - oh * 6;
    tbase1 = s * 6400 + (oh * 40 + ow * 2) * 16 + half * 8;
    if (wv == 0) {
      r = 256 + l31;
      s = r / 36; pos = r - s * 36; oh = pos / 6; ow = pos - oh * 6;
      tbase2 = s * 6400 + (oh * 40 + ow * 2) * 16 + half * 8;
    }
  }
  f32x16 acc0 = zero16(), acc1 = zero16(), acc2 = zero16();

  for (int kh = 0; kh < 9; ++kh) {
    __syncthreads();
    {
      const unsigned int* g = (const unsigned int*)(wBg + kh * 4608);
      unsigned int* s = (unsigned int*)sB;
#pragma unroll
      for (int i = 0; i < 9; ++i) s[t + i * 256] = g[t + i * 256];
    }
    __syncthreads();
    int abase = kh * 320;
#pragma unroll
    for (int kw = 0; kw < 9; ++kw) {
      f16x8 bf = *(const f16x8*)(sB + kw * 512 + lane * 8);
      f16x8 a0 = *(const f16x8*)(sX + tbase0 + abase + kw * 16);
      acc0 = __builtin_amdgcn_mfma_f32_32x32x16_f16(a0, bf, acc0, 0, 0, 0);
      f16x8 a1 = *(const f16x8*)(sX + tbase1 + abase + kw * 16);
      acc1 = __builtin_amdgcn_mfma_f32_32x32x16_f16(a1, bf, acc1, 0, 0, 0);
      if (wv == 0) {
        f16x8 a2 = *(const f16x8*)(sX + tbase2 + abase + kw * 16);
        acc2 = __builtin_amdgcn_mfma_f32_32x32x16_f16(a2, bf, acc2, 0, 0, 0);
      }
    }
  }
  float bv = bias[l31];
  int c8 = l31 >> 2;
  int ibco = (l31 & 3) * 36;
#pragma unroll
  for (int reg = 0; reg < 16; ++reg) {
    int rbase = (reg & 3) + 8 * (reg >> 2) + 4 * half;
    {
      int r = wv * 32 + rbase;
      int s = r / 36, pos = r - s * 36;
      u[(size_t)(bbase + s) * 1152 + (ibco + pos) * 8 + c8] = acc0[reg] + bv;
    }
    {
      int r = wv * 32 + 128 + rbase;
      int s = r / 36, pos = r - s * 36;
      u[(size_t)(bbase + s) * 1152 + (ibco + pos) * 8 + c8] = acc1[reg] + bv;
    }
    if (wv == 0) {
      int r = 256 + rbase;
      int s = r / 36, pos = r - s * 36;
      u[(size_t)(bbase + s) * 1152 + (ibco + pos) * 8 + c8] = acc2[reg] + bv;
    }
  }
}

// routing2: block = 2 samples, 512 threads. u_hat f16 in LDS only.
// W_route f16 (369 KB) streamed from L2 once per block, shared by both samples.
__global__ __launch_bounds__(512) void routing2_kernel(
    const float* __restrict__ u, const unsigned int* __restrict__ wPr,
    float* __restrict__ out, int B) {
  __shared__ unsigned int uhh[2][11808];   // [sl][i*82+dp] f16 d-pairs (80 used)
  __shared__ unsigned int ush[2][576];     // u f16 c-pairs [i][4]
  __shared__ float blog[2][1440];
  __shared__ float cc[2][1440];
  __shared__ float spart[2][480];
  __shared__ float ss[2][160];
  __shared__ float vv[2][160];
  __shared__ unsigned int vvh[2][80];
  int b0 = blockIdx.x * 2, t = threadIdx.x;
  for (int j = t; j < 1152; j += 512) {
    int sl2 = j / 576, k = j - sl2 * 576;
    float2 p = *(const float2*)(u + (size_t)(b0 + sl2) * 1152 + k * 2);
    ush[sl2][k] = pkh2(p.x, p.y);
  }
  for (int j = t; j < 2880; j += 512) blog[j / 1440][j % 1440] = 0.f;
  __syncthreads();

  const uint4* W4 = (const uint4*)wPr;   // [i*160 + o*16 + d] rows of 8 f16
  for (int idx = t; idx < 11520; idx += 512) {
    int i = idx / 80, dp = idx - i * 80;          // dp = o*8 + dd
    int row = (dp >> 3) * 16 + (dp & 7) * 2;      // o*16 + dd*2
    uint4 w0 = W4[i * 160 + row];
    uint4 w1 = W4[i * 160 + row + 1];
#pragma unroll
    for (int sl2 = 0; sl2 < 2; ++sl2) {
      const uint2* up = (const uint2*)&ush[sl2][i * 4];
      uint2 ua = up[0], ub = up[1];
      half2_t u0 = h2(ua.x), u1 = h2(ua.y), u2 = h2(ub.x), u3 = h2(ub.y);
      float a0 = fdot2f(h2(w0.x), u0,
                 fdot2f(h2(w0.y), u1,
                 fdot2f(h2(w0.z), u2, fdot2f(h2(w0.w), u3, 0.f))));
      float a1 = fdot2f(h2(w1.x), u0,
                 fdot2f(h2(w1.y), u1,
                 fdot2f(h2(w1.z), u2, fdot2f(h2(w1.w), u3, 0.f))));
      uhh[sl2][i * 82 + dp] = pkh2(a0, a1);
    }
  }
  __syncthreads();

  int sl = t >> 8, tl = t & 255;
  for (int it = 0; it < 3; ++it) {
    if (it > 0) {
      if (tl < 144) {
        const float* br = &blog[sl][tl * 10];
        float mx = br[0];
#pragma unroll
        for (int o = 1; o < 10; ++o) mx = fmaxf(mx, br[o]);
        float e[10];
        float sum = 0.f;
#pragma unroll
        for (int o = 0; o < 10; ++o) { e[o] = __expf(br[o] - mx); sum += e[o]; }
        float inv = 1.0f / sum;
#pragma unroll
        for (int o = 0; o < 10; ++o) cc[sl][tl * 10 + o] = e[o] * inv;
      }
      __syncthreads();
    }
    // s partials: per sample, 240 lanes = 3 i-chunks x 80 d-pairs
    if (tl < 240) {
      int ch = tl / 80, dp = tl - ch * 80;
      int o = dp >> 3;
      float a0 = 0.f, a1 = 0.f;
      int i0 = ch * 48;
      if (it == 0) {
        for (int i = i0; i < i0 + 48; ++i) {
          half2_t h = h2(uhh[sl][i * 82 + dp]);
          a0 += (float)h[0]; a1 += (float)h[1];
        }
      } else {
        for (int i = i0; i < i0 + 48; ++i) {
          float c = cc[sl][i * 10 + o];
          half2_t h = h2(uhh[sl][i * 82 + dp]);
          a0 += c * (float)h[0]; a1 += c * (float)h[1];
        }
      }
      spart[sl][ch * 160 + dp * 2] = a0;
      spart[sl][ch * 160 + dp * 2 + 1] = a1;
    }
    __syncthreads();
    if (tl < 160) {
      float s = spart[sl][tl] + spart[sl][160 + tl] + spart[sl][320 + tl];
      ss[sl][tl] = (it == 0) ? s * 0.1f : s;   // it==0: softmax of zeros = 0.1
    }
    __syncthreads();
    if (tl < 10) {
      float sq = 0.f;
#pragma unroll
      for (int d = 0; d < 16; ++d) { float x = ss[sl][tl * 16 + d]; sq += x * x; }
      float coef = (sq / (1.0f + sq)) / sqrtf(sq + 1e-8f);
#pragma unroll
      for (int q = 0; q < 8; ++q) {
        float v0 = coef * ss[sl][tl * 16 + 2 * q];
        float v1 = coef * ss[sl][tl * 16 + 2 * q + 1];
        vv[sl][tl * 16 + 2 * q] = v0;
        vv[sl][tl * 16 + 2 * q + 1] = v1;
        vvh[sl][tl * 8 + q] = pkh2(v0, v1);
      }
      if (it == 2) out[(b0 + sl) * 10 + tl] = coef * sqrtf(sq);   // pred
    }
    __syncthreads();
    if (it < 2) {
      for (int idx = t; idx < 2880; idx += 512) {
        int s2 = idx / 1440, r = idx - s2 * 1440;
        int i = r / 10, o = r - i * 10;
        const uint2* uhp = (const uint2*)&uhh[s2][i * 82 + o * 8];
        const uint2* vp = (const uint2*)&vvh[s2][o * 8];
        float dot = 0.f;
#pragma unroll
        for (int q = 0; q < 4; ++q) {
          uint2 A = uhp[q], V = vp[q];
          dot = fdot2f(h2(A.x), h2(V.x), fdot2f(h2(A.y), h2(V.y), dot));
        }
        blog[s2][r] += dot;
      }
      __syncthreads();
    }
  }
  if (tl < 160) out[B * 10 + (b0 + sl) * 160 + tl] = vv[sl][tl];
}

extern "C" void kernel_launch(void* const* d_in, const int* in_sizes, int n_in,
                              void* d_out, int out_size, void* d_ws, size_t ws_size,
                              hipStream_t stream) {
  const float* in = (const float*)d_in[0];
  const float* w1 = (const float*)d_in[1];
  const float* b1 = (const float*)d_in[2];
  const float* w2 = (const float*)d_in[3];
  const float* b2 = (const float*)d_in[4];
  const float* Wr = (const float*)d_in[5];
  float* out = (float*)d_out;
  int B = in_sizes[0] / 784;
  float* wsf = (float*)d_ws;

  float* u = wsf;                                    // [B][1152] f32
  _Float16* x1t = (_Float16*)(wsf + (size_t)B * 1152);  // B*6400 f16 = B*3200 f
  float* tail = wsf + (size_t)B * 1152 + (size_t)B * 3200;
  _Float16* wBg = (_Float16*)tail;                   // 41472 f16 = 20736 f
  unsigned int* wPr = (unsigned int*)(tail + 20736); // 92160 dw

  packWB<<<162, 256, 0, stream>>>(w2, wBg);
  packWr<<<360, 256, 0, stream>>>(Wr, wPr);
  conv1_kernel<<<B, 320, 0, stream>>>(in, w1, b1, x1t);
  conv2_kernel<<<B / 8, 256, 0, stream>>>(x1t, wBg, b2, u);
  routing2_kernel<<<B / 2, 512, 0, stream>>>(u, wPr, out, B);
}